// Round 7
// baseline (857.659 us; speedup 1.0000x reference)
//
#include <hip/hip_runtime.h>

// N=1024, D=16, H=32, 3H=96.  All tensors fp32 (per reference dtypes).

typedef _Float16 hv2 __attribute__((ext_vector_type(2)));

__device__ __forceinline__ unsigned rlu(unsigned v, int k) {
    return (unsigned)__builtin_amdgcn_readlane((int)v, k);
}
// pack two fp32 -> half2 bits (v_cvt_pkrtz_f16_f32)
__device__ __forceinline__ unsigned pkh(float a, float b) {
    auto t = __builtin_amdgcn_cvt_pkrtz(a, b);   // native return type
    return __builtin_bit_cast(unsigned, t);
}
// dot2: c += a.x*b.x + a.y*b.y   (f16 inputs, f32 accumulate)
#if __has_builtin(__builtin_amdgcn_fdot2)
__device__ __forceinline__ float d2(unsigned a, unsigned b, float c) {
    return __builtin_amdgcn_fdot2(__builtin_bit_cast(hv2, a),
                                  __builtin_bit_cast(hv2, b), c, false);
}
#else
__device__ __forceinline__ float d2(unsigned a, unsigned b, float c) {
    hv2 x = __builtin_bit_cast(hv2, a), y = __builtin_bit_cast(hv2, b);
    return fmaf((float)x.x, (float)y.x, fmaf((float)x.y, (float)y.y, c));
}
#endif
// neighbor (lane^1) value WITHOUT the LDS crossbar: DPP quad_perm(1,0,3,2).
#if __has_builtin(__builtin_amdgcn_mov_dpp)
__device__ __forceinline__ float nbr1(float v) {
    return __int_as_float(
        __builtin_amdgcn_mov_dpp(__float_as_int(v), 0xB1, 0xF, 0xF, true));
}
#else
__device__ __forceinline__ float nbr1(float v) {   // fallback: ds_swizzle xor1
    return __int_as_float(__builtin_amdgcn_ds_swizzle(__float_as_int(v), 0x041F));
}
#endif

// ---------------------------------------------------------------------------
// K1: stage-1 pairwise split.  A[i,h] = sum_d (w[h,d]-w[h,16+d])*x[i,d] + b[h]
//                              B[j,h] = sum_d w[h,16+d]*x[j,d]
// relu(A[i,:]+B[j,:]) reconstructs out1[i,j,:] -- [N,N,H] never materialized.
// ---------------------------------------------------------------------------
__global__ void proj1_kernel(const float* __restrict__ x, const float* __restrict__ w,
                             const float* __restrict__ bias,
                             float* __restrict__ A, float* __restrict__ B) {
    int idx = blockIdx.x * 256 + threadIdx.x;      // 0..32767
    int i = idx >> 5, h = idx & 31;
    float sa = bias[h];
    float sb = 0.f;
#pragma unroll
    for (int d = 0; d < 16; ++d) {
        float xv = x[i * 16 + d];
        float wa = w[h * 32 + d];
        float wb = w[h * 32 + 16 + d];
        sa += (wa - wb) * xv;
        sb += wb * xv;
    }
    A[i * 32 + h] = sa;
    B[i * 32 + h] = sb;
}

__global__ void proj2_kernel(const float* __restrict__ h1, const float* __restrict__ w,
                             const float* __restrict__ bias,
                             float* __restrict__ A, float* __restrict__ B) {
    int idx = blockIdx.x * 256 + threadIdx.x;      // 0..32767
    int i = idx >> 5, h = idx & 31;
    float sa = bias[h];
    float sb = 0.f;
#pragma unroll
    for (int k = 0; k < 32; ++k) {
        float hv = h1[i * 32 + k];
        float wa = w[h * 64 + k];
        float wb = w[h * 64 + 32 + k];
        sa += (wa - wb) * hv;
        sb += wb * hv;
    }
    A[i * 32 + h] = sa;
    B[i * 32 + h] = sb;
}

// ---------------------------------------------------------------------------
// GRU: ONE WAVE per batch element, wave-synchronous, ZERO LDS ops in the loop.
// seq[b,t,:] = relu(A[b,:] + B[t,:]).  Gate order r,z,n (PyTorch).
//
// Lane l (m = l&31; both halves duplicate the chain) owns hidden index m and
// ALL SIX of its gate rows packed as f16 pairs (96 VGPRs):
//   wXr/wXz/wXn = wih rows m / 32+m / 64+m
//   wHr/wHz/wHn = whh rows m / 32+m / 64+m
// r_m, z_m, n_m, and the h-update are computed IN-LANE (no __shfl).
// o/h pair-packing uses DPP quad_perm (VALU) instead of ds_swizzle; the
// 32-value broadcasts are 16 v_readlane each.  The X-phase for step t+1
// (relu, pack, broadcast, 48 x-dots) is h-independent and overlaps step t's
// h-critical path.  Dist-2 global prefetch of the B row.
// ---------------------------------------------------------------------------
__global__ __launch_bounds__(64, 1) void gru_kernel(
    const float* __restrict__ A, const float* __restrict__ B,
    const float* __restrict__ wih, const float* __restrict__ whh,
    const float* __restrict__ bih, const float* __restrict__ bhh,
    float* __restrict__ h_out) {
    const int b = blockIdx.x;
    const int l = threadIdx.x;        // 0..63
    const int m = l & 31;

    unsigned wXr[16], wXz[16], wXn[16], wHr[16], wHz[16], wHn[16];
#pragma unroll
    for (int k = 0; k < 16; ++k) {
        wXr[k] = pkh(wih[m * 32 + 2 * k],        wih[m * 32 + 2 * k + 1]);
        wXz[k] = pkh(wih[(32 + m) * 32 + 2 * k], wih[(32 + m) * 32 + 2 * k + 1]);
        wXn[k] = pkh(wih[(64 + m) * 32 + 2 * k], wih[(64 + m) * 32 + 2 * k + 1]);
        wHr[k] = pkh(whh[m * 32 + 2 * k],        whh[m * 32 + 2 * k + 1]);
        wHz[k] = pkh(whh[(32 + m) * 32 + 2 * k], whh[(32 + m) * 32 + 2 * k + 1]);
        wHn[k] = pkh(whh[(64 + m) * 32 + 2 * k], whh[(64 + m) * 32 + 2 * k + 1]);
    }
    const float br = bih[m] + bhh[m];            // full r bias (x-acc seeded)
    const float bz = bih[32 + m] + bhh[32 + m];  // full z bias
    const float bxn = bih[64 + m];               // n-gate x bias
    const float bhn = bhh[64 + m];               // n-gate h bias

    const float a_r = A[b * 32 + m];             // replicated in both halves
    float h_l = 0.f;                             // h_m replicated in both halves

    unsigned hu2[16];                            // broadcast packed h
#pragma unroll
    for (int k = 0; k < 16; ++k) hu2[k] = 0u;

    // X-phase for t=0
    float xr, xz, xn;
    {
        float o0 = fmaxf(a_r + B[m], 0.f);
        unsigned opk = pkh(o0, nbr1(o0));        // even lanes: (o_2k, o_2k+1)
        xr = br; xz = bz; xn = bxn;
#pragma unroll
        for (int k = 0; k < 16; ++k) {
            unsigned ok = rlu(opk, 2 * k);
            xr = d2(wXr[k], ok, xr);
            xz = d2(wXz[k], ok, xz);
            xn = d2(wXn[k], ok, xn);
        }
    }
    float b_next = B[32 + m];                    // B row for t=1

#pragma unroll 2
    for (int t = 0; t < 1024; ++t) {
        // prefetch B row t+2 (consumed next iteration)
        float b_pref = B[((t + 2) & 1023) * 32 + m];

        // H-phase: depends on hu2 (critical chain), three interleaved chains
        float hr = 0.f, hz = 0.f, hn = bhn;
#pragma unroll
        for (int k = 0; k < 16; ++k) {
            hr = d2(wHr[k], hu2[k], hr);
            hz = d2(wHz[k], hu2[k], hz);
            hn = d2(wHn[k], hu2[k], hn);
        }

        // X-phase for t+1: independent of h, fills latency
        float nxr = br, nxz = bz, nxn = bxn;
        {
            float onext = fmaxf(a_r + b_next, 0.f);
            unsigned opk = pkh(onext, nbr1(onext));
#pragma unroll
            for (int k = 0; k < 16; ++k) {
                unsigned ok = rlu(opk, 2 * k);
                nxr = d2(wXr[k], ok, nxr);
                nxz = d2(wXz[k], ok, nxz);
                nxn = d2(wXn[k], ok, nxn);
            }
        }

        // gates -- ALL in-lane (r_m, z_m, n_m, h_m live in lane m of each half)
        float r = 1.f / (1.f + __expf(-(xr + hr)));
        float z = 1.f / (1.f + __expf(-(xz + hz)));
        float npre = xn + r * hn;
        float n = 1.f - 2.f / (__expf(2.f * npre) + 1.f);   // tanh
        h_l = (1.f - z) * n + z * h_l;

        // broadcast new h (DPP pair-pack + 16 readlanes)
        unsigned hpk = pkh(h_l, nbr1(h_l));
#pragma unroll
        for (int k = 0; k < 16; ++k) hu2[k] = rlu(hpk, 2 * k);

        xr = nxr; xz = nxz; xn = nxn;
        b_next = b_pref;
    }

    if (l < 32) h_out[b * 32 + m] = h_l;
}

// ---------------------------------------------------------------------------
// K5: classifier. out[i,o] = sum_k clf_w[o,k]*h2[i,k] + clf_b[o]  (fp32 out)
// ---------------------------------------------------------------------------
__global__ void clf_kernel(const float* __restrict__ h2v, const float* __restrict__ w,
                           const float* __restrict__ bias, float* __restrict__ out) {
    int idx = blockIdx.x * 256 + threadIdx.x;      // 0..3071
    if (idx >= 3072) return;
    int i = idx / 3, o = idx - i * 3;
    float s = bias[o];
#pragma unroll
    for (int k = 0; k < 32; ++k) s += w[o * 32 + k] * h2v[i * 32 + k];
    out[idx] = s;
}

extern "C" void kernel_launch(void* const* d_in, const int* in_sizes, int n_in,
                              void* d_out, int out_size, void* d_ws, size_t ws_size,
                              hipStream_t stream) {
    const float* x       = (const float*)d_in[0];
    const float* p1w     = (const float*)d_in[1];
    const float* p1b     = (const float*)d_in[2];
    const float* g1_wih  = (const float*)d_in[3];
    const float* g1_whh  = (const float*)d_in[4];
    const float* g1_bih  = (const float*)d_in[5];
    const float* g1_bhh  = (const float*)d_in[6];
    const float* p2w     = (const float*)d_in[7];
    const float* p2b     = (const float*)d_in[8];
    const float* g2_wih  = (const float*)d_in[9];
    const float* g2_whh  = (const float*)d_in[10];
    const float* g2_bih  = (const float*)d_in[11];
    const float* g2_bhh  = (const float*)d_in[12];
    const float* clfw    = (const float*)d_in[13];
    const float* clfb    = (const float*)d_in[14];

    // Workspace layout (reused across stages; 3 x 32768 floats = 384 KB):
    float* ws = (float*)d_ws;
    float* A  = ws;              // A1 then A2
    float* Bt = ws + 32768;      // B1 then B2
    float* h  = ws + 65536;      // h1 then h2

    proj1_kernel<<<128, 256, 0, stream>>>(x, p1w, p1b, A, Bt);
    gru_kernel<<<1024, 64, 0, stream>>>(A, Bt, g1_wih, g1_whh, g1_bih, g1_bhh, h);
    proj2_kernel<<<128, 256, 0, stream>>>(h, p2w, p2b, A, Bt);
    gru_kernel<<<1024, 64, 0, stream>>>(A, Bt, g2_wih, g2_whh, g2_bih, g2_bhh, h);
    clf_kernel<<<12, 256, 0, stream>>>(h, clfw, clfb, (float*)d_out);
}